// Round 1
// baseline (379.648 us; speedup 1.0000x reference)
//
#include <hip/hip_runtime.h>

#define Bb 8
#define Cc 8
#define Ff 257
#define Tt 1500
#define P2 750            // Tt/2 (float2 elements)
#define P4 375            // Tt/4 (float4 elements)
#define BF (Bb*Ff)        // 2056

__device__ __forceinline__ constexpr int utIdx(int c, int d) { return c*(17-c)/2 + (d-c); }      // c<=d, 36 vals
__device__ __forceinline__ constexpr int odIdx(int c, int d) { return 7*c - c*(c-1)/2 + (d-c-1); } // c<d, 28 vals

constexpr float EPSv   = 1e-8f;
constexpr float PSDEPS = 1e-5f;
constexpr float IMADD  = 1e-5f + 1e-8f;   // +1j*PSD_EPS (inside _estimate_psd) +1j*eps (outside)

// ---------------- mask max, stage 1: partial max over F-chunks ----------------
__global__ void mask_pmax(const float* __restrict__ sm, const float* __restrict__ nm,
                          float* __restrict__ pmax_s, float* __restrict__ pmax_n) {
    int t  = blockIdx.x * 256 + threadIdx.x;
    int ch = blockIdx.y;
    int b  = blockIdx.z;
    if (t >= Tt) return;
    int f0 = ch * 33, f1 = min(Ff, f0 + 33);
    float ms = 0.f, mn = 0.f;
    for (int f = f0; f < f1; ++f) {
        ms = fmaxf(ms, fabsf(sm[(b*Ff + f)*Tt + t]));
        mn = fmaxf(mn, fabsf(nm[(b*Ff + f)*Tt + t]));
    }
    pmax_s[(b*8 + ch)*Tt + t] = ms;
    pmax_n[(b*8 + ch)*Tt + t] = mn;
}

// ---------------- mask max, stage 2: combine chunks -> 1/(max+eps) ----------------
__global__ void mask_inv(const float* __restrict__ pmax_s, const float* __restrict__ pmax_n,
                         float* __restrict__ inv_s, float* __restrict__ inv_n) {
    int t = blockIdx.x * 256 + threadIdx.x;
    int b = blockIdx.y;
    if (t >= Tt) return;
    float ms = 0.f, mn = 0.f;
    #pragma unroll
    for (int ch = 0; ch < 8; ++ch) {
        ms = fmaxf(ms, pmax_s[(b*8 + ch)*Tt + t]);
        mn = fmaxf(mn, pmax_n[(b*8 + ch)*Tt + t]);
    }
    inv_s[b*Tt + t] = 1.0f / (ms + EPSv);
    inv_n[b*Tt + t] = 1.0f / (mn + EPSv);
}

// ---------------- main fused kernel: one block (4 waves) per (b,f) ----------------
// Wave specialization: wave w -> (msel = w>>1: 0 speech / 1 noise,
//                                 part = w&1 : 0 real(36 accs) / 1 imag(28 accs)).
// Each wave alone covers all 750 float2 time samples (lane = t index within round),
// so loads are fully coalesced (512 B / instruction) and per-thread state is
// <=36 accs + 32 load regs (~95 VGPR) -> 4 waves/SIMD with batched loads per round
// (one vmcnt exposure per 18-load round instead of serialized channel round-trips).
__global__ __launch_bounds__(256, 4) void mvdr_main(
    const float* __restrict__ smask, const float* __restrict__ nmask,
    const float* __restrict__ cmr,   const float* __restrict__ cmi,
    const float* __restrict__ inv_s, const float* __restrict__ inv_n,
    float* __restrict__ out)
{
    const int blk = blockIdx.x;
    const int b = blk / Ff, f = blk % Ff;
    const int tid  = threadIdx.x;
    const int wid  = tid >> 6;         // wave id [0,4)
    const int lane = tid & 63;
    const int msel = __builtin_amdgcn_readfirstlane(wid >> 1);   // 0: speech, 1: noise
    const int part = __builtin_amdgcn_readfirstlane(wid & 1);    // 0: real set, 1: imag set

    const float2* sm2 = (const float2*)smask + (b*Ff + f)*P2;
    const float2* nm2 = (const float2*)nmask + (b*Ff + f)*P2;
    const float2* is2 = (const float2*)inv_s + b*P2;
    const float2* in2 = (const float2*)inv_n + b*P2;
    const float2* m2  = msel ? nm2 : sm2;
    const float2* iv2 = msel ? in2 : is2;
    const int cstride = Ff * P2;                       // float2 per (b,c) plane
    const float2* xr2 = (const float2*)cmr + (b*Cc)*cstride + f*P2;
    const float2* xi2 = (const float2*)cmi + (b*Cc)*cstride + f*P2;

    // ---- Phase A: weighted covariance accumulation ----
    float acc[36];
    #pragma unroll
    for (int v = 0; v < 36; ++v) acc[v] = 0.f;
    float summ = 0.f;

    auto body = [&](int p) {
        float2 mk = m2[p], iv = iv2[p];
        float2 xr[8], xi[8];
        #pragma unroll
        for (int c = 0; c < 8; ++c) { xr[c] = xr2[p + c*cstride]; xi[c] = xi2[p + c*cstride]; }
        float mx = mk.x * iv.x, my = mk.y * iv.y;
        if (part == 0) {
            summ += mx + my;
            #pragma unroll
            for (int c = 0; c < 8; ++c) {
                float ax = mx*xr[c].x, ay = my*xr[c].y, bx = mx*xi[c].x, by = my*xi[c].y;
                #pragma unroll
                for (int d = c; d < 8; ++d) {
                    const int k = utIdx(c, d);
                    float t0 = acc[k];
                    t0 = fmaf(ax, xr[d].x, t0); t0 = fmaf(bx, xi[d].x, t0);
                    t0 = fmaf(ay, xr[d].y, t0); t0 = fmaf(by, xi[d].y, t0);
                    acc[k] = t0;
                }
            }
        } else {
            #pragma unroll
            for (int c = 0; c < 8; ++c) {
                float ax = mx*xr[c].x, ay = my*xr[c].y, bx = mx*xi[c].x, by = my*xi[c].y;
                #pragma unroll
                for (int d = c + 1; d < 8; ++d) {
                    const int j = odIdx(c, d);
                    float t1 = acc[j];
                    t1 = fmaf(bx, xr[d].x, t1); t1 = fmaf(-ax, xi[d].x, t1);
                    t1 = fmaf(by, xr[d].y, t1); t1 = fmaf(-ay, xi[d].y, t1);
                    acc[j] = t1;
                }
            }
        }
    };

    int p = lane;
    #pragma unroll 1
    for (int it = 0; it < 11; ++it, p += 64) body(p);   // p <= 703 always valid
    if (p < P2) body(p);                                // tail: lanes 0..45

    // ---- per-wave butterfly reduction + store to LDS ----
    __shared__ float Sre[36], Sim[28], Nre[36], Nim[28];
    __shared__ float sumSN[2];

    if (part == 0) {
        #pragma unroll
        for (int o = 1; o <= 32; o <<= 1) {
            summ += __shfl_xor(summ, o, 64);
            #pragma unroll
            for (int v = 0; v < 36; ++v) acc[v] += __shfl_xor(acc[v], o, 64);
        }
        if (lane == 0) {
            float* dst = msel ? Nre : Sre;
            #pragma unroll
            for (int v = 0; v < 36; ++v) dst[v] = acc[v];
            sumSN[msel] = summ;
        }
    } else {
        #pragma unroll
        for (int o = 1; o <= 32; o <<= 1) {
            #pragma unroll
            for (int v = 0; v < 28; ++v) acc[v] += __shfl_xor(acc[v], o, 64);
        }
        if (lane == 0) {
            float* dst = msel ? Nim : Sim;
            #pragma unroll
            for (int v = 0; v < 28; ++v) dst[v] = acc[v];
        }
    }
    __syncthreads();

    // ---- build S matrix and augmented [N | I] in LDS (threads 0..63) ----
    __shared__ float SreM[64], SimM[64];
    __shared__ float Are[128], Aim[128];
    __shared__ float dre[8], dim_[8], wre[8], wim[8];

    if (tid < 64) {
        const float den_s = fmaxf(sumSN[0], PSDEPS);
        const float den_n = fmaxf(sumSN[1], PSDEPS);
        int cc_, dd_;
        float sv, nv;
        if (tid < 36) {
            int k = tid, c = 0; while (k >= 8 - c) { k -= 8 - c; ++c; } cc_ = c; dd_ = c + k;
            sv = Sre[tid] / den_s; nv = Nre[tid] / den_n;
        } else {
            int k = tid - 36, c = 0; while (k >= 7 - c) { k -= 7 - c; ++c; } cc_ = c; dd_ = c + k + 1;
            sv = Sim[tid - 36] / den_s; nv = Nim[tid - 36] / den_n;
        }
        if (tid < 36) {
            SreM[cc_*8 + dd_] = sv; SreM[dd_*8 + cc_] = sv;
            float nvd = nv + (cc_ == dd_ ? EPSv : 0.f);   // + eye*eps on noise diag
            Are[cc_*16 + dd_] = nvd; Are[dd_*16 + cc_] = nvd;
            if (cc_ == dd_) { SimM[cc_*8 + cc_] = IMADD; Aim[cc_*16 + cc_] = IMADD; }
        } else {
            SimM[cc_*8 + dd_] = IMADD + sv; SimM[dd_*8 + cc_] = IMADD - sv;
            Aim[cc_*16 + dd_] = IMADD + nv; Aim[dd_*16 + cc_] = IMADD - nv;
        }
        int r = tid >> 3, j = tid & 7;                    // identity right half
        Are[r*16 + 8 + j] = (r == j) ? 1.f : 0.f;
        Aim[r*16 + 8 + j] = 0.f;
    }
    __syncthreads();

    // ---- Gauss-Jordan inverse of N (unpivoted; N ~ HPD + tiny perturbation) ----
    {
        const bool act = tid < 64;
        const int r = (tid >> 3) & 7, cA = tid & 7;
        for (int k = 0; k < 8; ++k) {
            float pr = Are[k*16 + k], pi = Aim[k*16 + k];
            float idn = 1.0f / (pr*pr + pi*pi);
            float ipr = pr*idn, ipi = -pi*idn;
            if (act && r == k) {
                float ar0 = Are[k*16 + cA],     ai0 = Aim[k*16 + cA];
                Are[k*16 + cA]     = ar0*ipr - ai0*ipi; Aim[k*16 + cA]     = ar0*ipi + ai0*ipr;
                float ar1 = Are[k*16 + cA + 8], ai1 = Aim[k*16 + cA + 8];
                Are[k*16 + cA + 8] = ar1*ipr - ai1*ipi; Aim[k*16 + cA + 8] = ar1*ipi + ai1*ipr;
            }
            __syncthreads();
            float fr = Are[r*16 + k], fi = Aim[r*16 + k];
            float p0r = Are[k*16 + cA],     p0i = Aim[k*16 + cA];
            float p1r = Are[k*16 + cA + 8], p1i = Aim[k*16 + cA + 8];
            float o0r = 0.f, o0i = 0.f, o1r = 0.f, o1i = 0.f;
            if (r != k) {
                o0r = Are[r*16 + cA]     - (fr*p0r - fi*p0i);
                o0i = Aim[r*16 + cA]     - (fr*p0i + fi*p0r);
                o1r = Are[r*16 + cA + 8] - (fr*p1r - fi*p1i);
                o1i = Aim[r*16 + cA + 8] - (fr*p1i + fi*p1r);
            }
            __syncthreads();
            if (act && r != k) {
                Are[r*16 + cA]     = o0r; Aim[r*16 + cA]     = o0i;
                Are[r*16 + cA + 8] = o1r; Aim[r*16 + cA + 8] = o1i;
            }
            __syncthreads();
        }
    }

    // ---- u = inv@S e0, partial traces ----
    if (tid < 8) {
        int c = tid;
        float ur = 0.f, ui = 0.f, tr_r = 0.f, tr_i = 0.f;
        #pragma unroll
        for (int j = 0; j < 8; ++j) {
            float vr = Are[c*16 + 8 + j], vi = Aim[c*16 + 8 + j] + EPSv;  // inv + 1j*eps
            float s0r = SreM[j*8 + 0], s0i = SimM[j*8 + 0];
            ur += vr*s0r - vi*s0i; ui += vr*s0i + vi*s0r;
            float scr = SreM[j*8 + c], sci = SimM[j*8 + c];
            tr_r += vr*scr - vi*sci; tr_i += vr*sci + vi*scr;
        }
        dre[c] = tr_r; dim_[c] = tr_i;
        wre[c] = ur;   wim[c]  = ui;
    }
    __syncthreads();
    if (tid < 8) {
        float tr_r = EPSv, tr_i = 0.f;
        #pragma unroll
        for (int j = 0; j < 8; ++j) { tr_r += dre[j]; tr_i += dim_[j]; }
        float idn = 1.0f / (tr_r*tr_r + tr_i*tr_i);
        float ur = wre[tid], ui = wim[tid];
        wre[tid] = (ur*tr_r + ui*tr_i) * idn;     // w = u * conj(tr) / |tr|^2
        wim[tid] = (ui*tr_r - ur*tr_i) * idn;
    }
    __syncthreads();

    // ---- Phase B: out[b,f,t] = sum_c conj(w_c) * x_c(t), float4, 256 threads ----
    float wr[8], wi[8];
    #pragma unroll
    for (int c = 0; c < 8; ++c) { wr[c] = wre[c]; wi[c] = wim[c]; }

    const int cstride4 = Ff * P4;                       // float4 per (b,c) plane
    const float4* xr4 = (const float4*)xr2;             // rows are 16B-aligned (6000 B pitch)
    const float4* xi4 = (const float4*)xi2;
    float4* outr4 = (float4*)out + (b*Ff + f)*P4;
    float4* outi4 = (float4*)out + (Bb*Ff)*P4 + (b*Ff + f)*P4;
    for (int pp = tid; pp < P4; pp += 256) {
        float rx = 0.f, ry = 0.f, rz = 0.f, rw = 0.f;
        float ix = 0.f, iy = 0.f, iz = 0.f, iw = 0.f;
        #pragma unroll
        for (int c = 0; c < 8; ++c) {
            float4 a  = xr4[pp + c*cstride4];
            float4 bb = xi4[pp + c*cstride4];
            rx = fmaf(wr[c], a.x, fmaf(wi[c], bb.x, rx));
            ry = fmaf(wr[c], a.y, fmaf(wi[c], bb.y, ry));
            rz = fmaf(wr[c], a.z, fmaf(wi[c], bb.z, rz));
            rw = fmaf(wr[c], a.w, fmaf(wi[c], bb.w, rw));
            ix = fmaf(wr[c], bb.x, fmaf(-wi[c], a.x, ix));
            iy = fmaf(wr[c], bb.y, fmaf(-wi[c], a.y, iy));
            iz = fmaf(wr[c], bb.z, fmaf(-wi[c], a.z, iz));
            iw = fmaf(wr[c], bb.w, fmaf(-wi[c], a.w, iw));
        }
        outr4[pp] = make_float4(rx, ry, rz, rw);
        outi4[pp] = make_float4(ix, iy, iz, iw);
    }
}

extern "C" void kernel_launch(void* const* d_in, const int* in_sizes, int n_in,
                              void* d_out, int out_size, void* d_ws, size_t ws_size,
                              hipStream_t stream) {
    const float* smask = (const float*)d_in[0];
    const float* nmask = (const float*)d_in[1];
    const float* cmr   = (const float*)d_in[2];
    const float* cmi   = (const float*)d_in[3];
    float* ws = (float*)d_ws;
    float* pmax_s = ws;                 // 8*8*1500 = 96000 floats
    float* pmax_n = ws + 96000;         // 96000
    float* inv_s  = ws + 192000;        // 12000
    float* inv_n  = ws + 204000;        // 12000  (total 864 KB)

    mask_pmax<<<dim3(6, 8, 8), 256, 0, stream>>>(smask, nmask, pmax_s, pmax_n);
    mask_inv <<<dim3(6, 8),    256, 0, stream>>>(pmax_s, pmax_n, inv_s, inv_n);
    mvdr_main<<<BF, 256, 0, stream>>>(smask, nmask, cmr, cmi, inv_s, inv_n, (float*)d_out);
}

// Round 2
// 310.002 us; speedup vs baseline: 1.2247x; 1.2247x over previous
//
#include <hip/hip_runtime.h>

#define Bb 8
#define Cc 8
#define Ff 257
#define Tt 1500
#define P2 750            // Tt/2 (float2 elements)
#define P4 375            // Tt/4 (float4 elements)
#define BF (Bb*Ff)        // 2056

__device__ __forceinline__ constexpr int utIdx(int c, int d) { return c*(17-c)/2 + (d-c); }      // c<=d, 36 vals
__device__ __forceinline__ constexpr int odIdx(int c, int d) { return 7*c - c*(c-1)/2 + (d-c-1); } // c<d, 28 vals

constexpr float EPSv   = 1e-8f;
constexpr float PSDEPS = 1e-5f;
constexpr float IMADD  = 1e-5f + 1e-8f;   // +1j*PSD_EPS (inside _estimate_psd) +1j*eps (outside)

// ---------------- mask max, stage 1: partial max over F-chunks ----------------
__global__ void mask_pmax(const float* __restrict__ sm, const float* __restrict__ nm,
                          float* __restrict__ pmax_s, float* __restrict__ pmax_n) {
    int t  = blockIdx.x * 256 + threadIdx.x;
    int ch = blockIdx.y;
    int b  = blockIdx.z;
    if (t >= Tt) return;
    int f0 = ch * 33, f1 = min(Ff, f0 + 33);
    float ms = 0.f, mn = 0.f;
    for (int f = f0; f < f1; ++f) {
        ms = fmaxf(ms, fabsf(sm[(b*Ff + f)*Tt + t]));
        mn = fmaxf(mn, fabsf(nm[(b*Ff + f)*Tt + t]));
    }
    pmax_s[(b*8 + ch)*Tt + t] = ms;
    pmax_n[(b*8 + ch)*Tt + t] = mn;
}

// ---------------- mask max, stage 2: combine chunks -> 1/(max+eps) ----------------
__global__ void mask_inv(const float* __restrict__ pmax_s, const float* __restrict__ pmax_n,
                         float* __restrict__ inv_s, float* __restrict__ inv_n) {
    int t = blockIdx.x * 256 + threadIdx.x;
    int b = blockIdx.y;
    if (t >= Tt) return;
    float ms = 0.f, mn = 0.f;
    #pragma unroll
    for (int ch = 0; ch < 8; ++ch) {
        ms = fmaxf(ms, pmax_s[(b*8 + ch)*Tt + t]);
        mn = fmaxf(mn, pmax_n[(b*8 + ch)*Tt + t]);
    }
    inv_s[b*Tt + t] = 1.0f / (ms + EPSv);
    inv_n[b*Tt + t] = 1.0f / (mn + EPSv);
}

// ---------------- main fused kernel: one block (4 waves) per (b,f) ----------------
// Wave specialization: wave w -> (msel = w>>1: 0 speech / 1 noise,
//                                 part = w&1 : 0 real(36 accs) / 1 imag(28 accs)).
// Each wave alone covers all 750 float2 time samples (lane = t index within round),
// so loads are fully coalesced (512 B / instruction).
// amdgpu_waves_per_eu(4,4): pin the allocator at exactly 4 waves/SIMD (128 VGPR
// cap AND floor). Round 1 showed that with a [4,8] range the backend chased
// 8 waves/SIMD (64 VGPR) and spilled ~120 MB of scratch per dispatch
// (WRITE_SIZE 24->144 MB). Kernel needs ~90-110 VGPR; 4 waves/SIMD = 16
// waves/CU is plenty of TLP for the one vmcnt exposure per 18-load round.
__global__ __launch_bounds__(256) __attribute__((amdgpu_waves_per_eu(4, 4)))
void mvdr_main(
    const float* __restrict__ smask, const float* __restrict__ nmask,
    const float* __restrict__ cmr,   const float* __restrict__ cmi,
    const float* __restrict__ inv_s, const float* __restrict__ inv_n,
    float* __restrict__ out)
{
    const int blk = blockIdx.x;
    const int b = blk / Ff, f = blk % Ff;
    const int tid  = threadIdx.x;
    const int wid  = tid >> 6;         // wave id [0,4)
    const int lane = tid & 63;
    const int msel = __builtin_amdgcn_readfirstlane(wid >> 1);   // 0: speech, 1: noise
    const int part = __builtin_amdgcn_readfirstlane(wid & 1);    // 0: real set, 1: imag set

    const float2* sm2 = (const float2*)smask + (b*Ff + f)*P2;
    const float2* nm2 = (const float2*)nmask + (b*Ff + f)*P2;
    const float2* is2 = (const float2*)inv_s + b*P2;
    const float2* in2 = (const float2*)inv_n + b*P2;
    const float2* m2  = msel ? nm2 : sm2;
    const float2* iv2 = msel ? in2 : is2;
    const int cstride = Ff * P2;                       // float2 per (b,c) plane
    const float2* xr2 = (const float2*)cmr + (b*Cc)*cstride + f*P2;
    const float2* xi2 = (const float2*)cmi + (b*Cc)*cstride + f*P2;

    // ---- Phase A: weighted covariance accumulation ----
    float acc[36];
    #pragma unroll
    for (int v = 0; v < 36; ++v) acc[v] = 0.f;
    float summ = 0.f;

    // 12 clamped iterations (single body instance; tail lanes get weight 0).
    #pragma unroll 1
    for (int it = 0; it < 12; ++it) {
        int p = lane + it*64;
        const float valid = (p < P2) ? 1.0f : 0.0f;
        p = (p < P2) ? p : (P2 - 1);
        float2 mk = m2[p], iv = iv2[p];
        float2 xr[8], xi[8];
        #pragma unroll
        for (int c = 0; c < 8; ++c) { xr[c] = xr2[p + c*cstride]; xi[c] = xi2[p + c*cstride]; }
        float mx = mk.x * iv.x * valid, my = mk.y * iv.y * valid;
        if (part == 0) {
            summ += mx + my;
            #pragma unroll
            for (int c = 0; c < 8; ++c) {
                float ax = mx*xr[c].x, ay = my*xr[c].y, bx = mx*xi[c].x, by = my*xi[c].y;
                #pragma unroll
                for (int d = c; d < 8; ++d) {
                    const int k = utIdx(c, d);
                    float t0 = acc[k];
                    t0 = fmaf(ax, xr[d].x, t0); t0 = fmaf(bx, xi[d].x, t0);
                    t0 = fmaf(ay, xr[d].y, t0); t0 = fmaf(by, xi[d].y, t0);
                    acc[k] = t0;
                }
            }
        } else {
            #pragma unroll
            for (int c = 0; c < 8; ++c) {
                float ax = mx*xr[c].x, ay = my*xr[c].y, bx = mx*xi[c].x, by = my*xi[c].y;
                #pragma unroll
                for (int d = c + 1; d < 8; ++d) {
                    const int j = odIdx(c, d);
                    float t1 = acc[j];
                    t1 = fmaf(bx, xr[d].x, t1); t1 = fmaf(-ax, xi[d].x, t1);
                    t1 = fmaf(by, xr[d].y, t1); t1 = fmaf(-ay, xi[d].y, t1);
                    acc[j] = t1;
                }
            }
        }
    }

    // ---- per-wave butterfly reduction + store to LDS ----
    __shared__ float Sre[36], Sim[28], Nre[36], Nim[28];
    __shared__ float sumSN[2];

    if (part == 0) {
        #pragma unroll
        for (int o = 1; o <= 32; o <<= 1) {
            summ += __shfl_xor(summ, o, 64);
            #pragma unroll
            for (int v = 0; v < 36; ++v) acc[v] += __shfl_xor(acc[v], o, 64);
        }
        if (lane == 0) {
            float* dst = msel ? Nre : Sre;
            #pragma unroll
            for (int v = 0; v < 36; ++v) dst[v] = acc[v];
            sumSN[msel] = summ;
        }
    } else {
        #pragma unroll
        for (int o = 1; o <= 32; o <<= 1) {
            #pragma unroll
            for (int v = 0; v < 28; ++v) acc[v] += __shfl_xor(acc[v], o, 64);
        }
        if (lane == 0) {
            float* dst = msel ? Nim : Sim;
            #pragma unroll
            for (int v = 0; v < 28; ++v) dst[v] = acc[v];
        }
    }
    __syncthreads();

    // ---- build S matrix and augmented [N | I] in LDS (threads 0..63) ----
    __shared__ float SreM[64], SimM[64];
    __shared__ float Are[128], Aim[128];
    __shared__ float dre[8], dim_[8], wre[8], wim[8];

    if (tid < 64) {
        const float den_s = fmaxf(sumSN[0], PSDEPS);
        const float den_n = fmaxf(sumSN[1], PSDEPS);
        int cc_, dd_;
        float sv, nv;
        if (tid < 36) {
            int k = tid, c = 0; while (k >= 8 - c) { k -= 8 - c; ++c; } cc_ = c; dd_ = c + k;
            sv = Sre[tid] / den_s; nv = Nre[tid] / den_n;
        } else {
            int k = tid - 36, c = 0; while (k >= 7 - c) { k -= 7 - c; ++c; } cc_ = c; dd_ = c + k + 1;
            sv = Sim[tid - 36] / den_s; nv = Nim[tid - 36] / den_n;
        }
        if (tid < 36) {
            SreM[cc_*8 + dd_] = sv; SreM[dd_*8 + cc_] = sv;
            float nvd = nv + (cc_ == dd_ ? EPSv : 0.f);   // + eye*eps on noise diag
            Are[cc_*16 + dd_] = nvd; Are[dd_*16 + cc_] = nvd;
            if (cc_ == dd_) { SimM[cc_*8 + cc_] = IMADD; Aim[cc_*16 + cc_] = IMADD; }
        } else {
            SimM[cc_*8 + dd_] = IMADD + sv; SimM[dd_*8 + cc_] = IMADD - sv;
            Aim[cc_*16 + dd_] = IMADD + nv; Aim[dd_*16 + cc_] = IMADD - nv;
        }
        int r = tid >> 3, j = tid & 7;                    // identity right half
        Are[r*16 + 8 + j] = (r == j) ? 1.f : 0.f;
        Aim[r*16 + 8 + j] = 0.f;
    }
    __syncthreads();

    // ---- Gauss-Jordan inverse of N (unpivoted; N ~ HPD + tiny perturbation) ----
    {
        const bool act = tid < 64;
        const int r = (tid >> 3) & 7, cA = tid & 7;
        for (int k = 0; k < 8; ++k) {
            float pr = Are[k*16 + k], pi = Aim[k*16 + k];
            float idn = 1.0f / (pr*pr + pi*pi);
            float ipr = pr*idn, ipi = -pi*idn;
            if (act && r == k) {
                float ar0 = Are[k*16 + cA],     ai0 = Aim[k*16 + cA];
                Are[k*16 + cA]     = ar0*ipr - ai0*ipi; Aim[k*16 + cA]     = ar0*ipi + ai0*ipr;
                float ar1 = Are[k*16 + cA + 8], ai1 = Aim[k*16 + cA + 8];
                Are[k*16 + cA + 8] = ar1*ipr - ai1*ipi; Aim[k*16 + cA + 8] = ar1*ipi + ai1*ipr;
            }
            __syncthreads();
            float fr = Are[r*16 + k], fi = Aim[r*16 + k];
            float p0r = Are[k*16 + cA],     p0i = Aim[k*16 + cA];
            float p1r = Are[k*16 + cA + 8], p1i = Aim[k*16 + cA + 8];
            float o0r = 0.f, o0i = 0.f, o1r = 0.f, o1i = 0.f;
            if (r != k) {
                o0r = Are[r*16 + cA]     - (fr*p0r - fi*p0i);
                o0i = Aim[r*16 + cA]     - (fr*p0i + fi*p0r);
                o1r = Are[r*16 + cA + 8] - (fr*p1r - fi*p1i);
                o1i = Aim[r*16 + cA + 8] - (fr*p1i + fi*p1r);
            }
            __syncthreads();
            if (act && r != k) {
                Are[r*16 + cA]     = o0r; Aim[r*16 + cA]     = o0i;
                Are[r*16 + cA + 8] = o1r; Aim[r*16 + cA + 8] = o1i;
            }
            __syncthreads();
        }
    }

    // ---- u = inv@S e0, partial traces ----
    if (tid < 8) {
        int c = tid;
        float ur = 0.f, ui = 0.f, tr_r = 0.f, tr_i = 0.f;
        #pragma unroll
        for (int j = 0; j < 8; ++j) {
            float vr = Are[c*16 + 8 + j], vi = Aim[c*16 + 8 + j] + EPSv;  // inv + 1j*eps
            float s0r = SreM[j*8 + 0], s0i = SimM[j*8 + 0];
            ur += vr*s0r - vi*s0i; ui += vr*s0i + vi*s0r;
            float scr = SreM[j*8 + c], sci = SimM[j*8 + c];
            tr_r += vr*scr - vi*sci; tr_i += vr*sci + vi*scr;
        }
        dre[c] = tr_r; dim_[c] = tr_i;
        wre[c] = ur;   wim[c]  = ui;
    }
    __syncthreads();
    if (tid < 8) {
        float tr_r = EPSv, tr_i = 0.f;
        #pragma unroll
        for (int j = 0; j < 8; ++j) { tr_r += dre[j]; tr_i += dim_[j]; }
        float idn = 1.0f / (tr_r*tr_r + tr_i*tr_i);
        float ur = wre[tid], ui = wim[tid];
        wre[tid] = (ur*tr_r + ui*tr_i) * idn;     // w = u * conj(tr) / |tr|^2
        wim[tid] = (ui*tr_r - ur*tr_i) * idn;
    }
    __syncthreads();

    // ---- Phase B: out[b,f,t] = sum_c conj(w_c) * x_c(t), float4, 256 threads ----
    float wr[8], wi[8];
    #pragma unroll
    for (int c = 0; c < 8; ++c) { wr[c] = wre[c]; wi[c] = wim[c]; }

    const int cstride4 = Ff * P4;                       // float4 per (b,c) plane
    const float4* xr4 = (const float4*)xr2;             // rows are 16B-aligned (6000 B pitch)
    const float4* xi4 = (const float4*)xi2;
    float4* outr4 = (float4*)out + (b*Ff + f)*P4;
    float4* outi4 = (float4*)out + (Bb*Ff)*P4 + (b*Ff + f)*P4;
    for (int pp = tid; pp < P4; pp += 256) {
        float rx = 0.f, ry = 0.f, rz = 0.f, rw = 0.f;
        float ix = 0.f, iy = 0.f, iz = 0.f, iw = 0.f;
        #pragma unroll
        for (int c = 0; c < 8; ++c) {
            float4 a  = xr4[pp + c*cstride4];
            float4 bb = xi4[pp + c*cstride4];
            rx = fmaf(wr[c], a.x, fmaf(wi[c], bb.x, rx));
            ry = fmaf(wr[c], a.y, fmaf(wi[c], bb.y, ry));
            rz = fmaf(wr[c], a.z, fmaf(wi[c], bb.z, rz));
            rw = fmaf(wr[c], a.w, fmaf(wi[c], bb.w, rw));
            ix = fmaf(wr[c], bb.x, fmaf(-wi[c], a.x, ix));
            iy = fmaf(wr[c], bb.y, fmaf(-wi[c], a.y, iy));
            iz = fmaf(wr[c], bb.z, fmaf(-wi[c], a.z, iz));
            iw = fmaf(wr[c], bb.w, fmaf(-wi[c], a.w, iw));
        }
        outr4[pp] = make_float4(rx, ry, rz, rw);
        outi4[pp] = make_float4(ix, iy, iz, iw);
    }
}

extern "C" void kernel_launch(void* const* d_in, const int* in_sizes, int n_in,
                              void* d_out, int out_size, void* d_ws, size_t ws_size,
                              hipStream_t stream) {
    const float* smask = (const float*)d_in[0];
    const float* nmask = (const float*)d_in[1];
    const float* cmr   = (const float*)d_in[2];
    const float* cmi   = (const float*)d_in[3];
    float* ws = (float*)d_ws;
    float* pmax_s = ws;                 // 8*8*1500 = 96000 floats
    float* pmax_n = ws + 96000;         // 96000
    float* inv_s  = ws + 192000;        // 12000
    float* inv_n  = ws + 204000;        // 12000  (total 864 KB)

    mask_pmax<<<dim3(6, 8, 8), 256, 0, stream>>>(smask, nmask, pmax_s, pmax_n);
    mask_inv <<<dim3(6, 8),    256, 0, stream>>>(pmax_s, pmax_n, inv_s, inv_n);
    mvdr_main<<<BF, 256, 0, stream>>>(smask, nmask, cmr, cmi, inv_s, inv_n, (float*)d_out);
}